// Round 1
// baseline (2184.986 us; speedup 1.0000x reference)
//
#include <hip/hip_runtime.h>
#include <cstdint>
#include <cstddef>

#define TB 2
#define TS 2048
#define TD 4096
#define TH 16
#define THD 256
#define TROT 64
#define TM (TB*TS)

typedef __attribute__((ext_vector_type(8))) short bf16x8;
typedef __attribute__((ext_vector_type(4))) float f32x4;

__device__ __forceinline__ unsigned short f2bf(float f) {
  union { float f; unsigned u; } v; v.f = f;
  return (unsigned short)((v.u + 0x7fffu + ((v.u >> 16) & 1u)) >> 16);
}

// ---------------- fp32 -> bf16 convert (vectorized) ----------------
__global__ __launch_bounds__(256) void k_cvt(const float* __restrict__ x,
                                             unsigned short* __restrict__ y, int n4) {
  int i = blockIdx.x * 256 + threadIdx.x;
  if (i >= n4) return;
  float4 v = reinterpret_cast<const float4*>(x)[i];
  ushort4 o;
  o.x = f2bf(v.x); o.y = f2bf(v.y); o.z = f2bf(v.z); o.w = f2bf(v.w);
  reinterpret_cast<ushort4*>(y)[i] = o;
}

// ---------------- GEMM: C = A (MxK,bf16) @ W^T (W: NxK,bf16) ----------------
// MODE 0: fp32 out, row-major [M,N]
// MODE 1: RoPE + transpose epilogue -> bf16 out [B,H,S,HD]
// MODE 2: bf16 out, row-major [M,N]
template<int MODE>
__global__ __launch_bounds__(256) void k_gemm(
    const unsigned short* __restrict__ A, const unsigned short* __restrict__ W,
    void* __restrict__ out, const float* __restrict__ sinp, const float* __restrict__ cosp)
{
  __shared__ unsigned short As[128*40];   // 128 x (32+8 pad)
  __shared__ unsigned short Bs[128*40];
  const int K = TD;
  const int t = threadIdx.x;
  const int m0 = blockIdx.y * 128, n0 = blockIdx.x * 128;
  const int w = t >> 6, l = t & 63, lr = l & 15, lh = l >> 4;
  const int wr = (w >> 1) * 64, wc = (w & 1) * 64;

  // staging chunk mapping: 512 chunks of 16B (128 rows x 4), 2 per thread
  const int c0 = t, c1 = t + 256;
  const int r0 = c0 >> 2, r1 = c1 >> 2;
  const int o0 = (c0 & 3) * 8, o1 = (c1 & 3) * 8;
  const unsigned short* pa0 = A + (size_t)(m0 + r0) * K + o0;
  const unsigned short* pa1 = A + (size_t)(m0 + r1) * K + o1;
  const unsigned short* pb0 = W + (size_t)(n0 + r0) * K + o0;
  const unsigned short* pb1 = W + (size_t)(n0 + r1) * K + o1;

  f32x4 acc[4][4];
#pragma unroll
  for (int i = 0; i < 4; ++i)
#pragma unroll
    for (int j = 0; j < 4; ++j) acc[i][j] = 0.f;

  uint4 ra0 = *(const uint4*)pa0, ra1 = *(const uint4*)pa1;
  uint4 rb0 = *(const uint4*)pb0, rb1 = *(const uint4*)pb1;

  for (int kt = 0; kt < K / 32; ++kt) {
    __syncthreads();
    *(uint4*)&As[r0*40 + o0] = ra0;
    *(uint4*)&As[r1*40 + o1] = ra1;
    *(uint4*)&Bs[r0*40 + o0] = rb0;
    *(uint4*)&Bs[r1*40 + o1] = rb1;
    __syncthreads();
    if (kt + 1 < K / 32) {           // prefetch next tile; latency hides under MFMAs
      int ko = (kt + 1) * 32;
      ra0 = *(const uint4*)(pa0 + ko); ra1 = *(const uint4*)(pa1 + ko);
      rb0 = *(const uint4*)(pb0 + ko); rb1 = *(const uint4*)(pb1 + ko);
    }
    bf16x8 af[4], bfr[4];
#pragma unroll
    for (int i = 0; i < 4; ++i) af[i]  = *(const bf16x8*)&As[(wr + i*16 + lr)*40 + lh*8];
#pragma unroll
    for (int i = 0; i < 4; ++i) bfr[i] = *(const bf16x8*)&Bs[(wc + i*16 + lr)*40 + lh*8];
#pragma unroll
    for (int i = 0; i < 4; ++i)
#pragma unroll
      for (int j = 0; j < 4; ++j)
        acc[i][j] = __builtin_amdgcn_mfma_f32_16x16x32_bf16(af[i], bfr[j], acc[i][j], 0, 0, 0);
  }

#pragma unroll
  for (int i = 0; i < 4; ++i)
#pragma unroll
    for (int j = 0; j < 4; ++j)
#pragma unroll
      for (int r = 0; r < 4; ++r) {
        int row = m0 + wr + i*16 + lh*4 + r;   // C layout: row=(l>>4)*4+r
        int col = n0 + wc + j*16 + lr;         //            col=l&15
        float x = acc[i][j][r];
        if constexpr (MODE == 0) {
          ((float*)out)[(size_t)row * TD + col] = x;
        } else if constexpr (MODE == 2) {
          ((unsigned short*)out)[(size_t)row * TD + col] = f2bf(x);
        } else {
          float part = __shfl_xor(x, 1, 64);   // partner d^1 lives in lane l^1
          int s = row & (TS - 1), b = row >> 11;
          int h = col >> 8, d = col & 255;
          float val = x;
          if (d < TROT) {
            float cc = cosp[s * TROT + d], ss = sinp[s * TROT + d];
            val = x * cc + ((d & 1) ? part : -part) * ss;  // GPT-J rotate_every_two
          }
          ((unsigned short*)out)[((size_t)(b * TH + h) * TS + s) * THD + d] = f2bf(val);
        }
      }
}

// ---------------- causal flash attention ----------------
// Qt,Kt: [B,H,S,HD] bf16.  Vb: [B,S,H,HD] bf16.  O: [B,S,H,HD] bf16.
// block = 4 waves; wave w owns q rows [q0+16w, q0+16w+16); KV tile = 32.
__global__ __launch_bounds__(256) void k_fattn(
    const unsigned short* __restrict__ Qt, const unsigned short* __restrict__ Kt,
    const unsigned short* __restrict__ Vb, unsigned short* __restrict__ O)
{
  __shared__ unsigned short Ks[32*264];    // 32 x (256+8 pad)
  __shared__ unsigned short Vs[256*40];    // transposed: [d][s_local], 32+8 pad
  __shared__ unsigned short Ps[4][16*40];  // per-wave P relayout buffer
  const int t = threadIdx.x, w = t >> 6, l = t & 63, lr = l & 15, lh = l >> 4;
  const int bh = blockIdx.y, b = bh >> 4, h = bh & 15;
  const int q0 = blockIdx.x * 64;

  bf16x8 qf[8];
  const unsigned short* qb = Qt + ((size_t)bh * TS + q0 + w*16 + lr) * THD;
#pragma unroll
  for (int kk = 0; kk < 8; ++kk) qf[kk] = *(const bf16x8*)(qb + kk*32 + lh*8);

  f32x4 oacc[16];
#pragma unroll
  for (int i = 0; i < 16; ++i) oacc[i] = 0.f;
  float mrow[4] = {-__builtin_inff(), -__builtin_inff(), -__builtin_inff(), -__builtin_inff()};
  float lrow[4] = {0.f, 0.f, 0.f, 0.f};

  const int jmax = (q0 >> 5) + 1;
  for (int j = 0; j <= jmax; ++j) {
    // stage K tile (32 x 256), coalesced 16B chunks
    const unsigned short* kb = Kt + ((size_t)bh * TS + j*32) * THD;
#pragma unroll
    for (int it = 0; it < 4; ++it) {
      int c = t + it*256;
      int row = c >> 5, col = (c & 31) * 8;
      *(uint4*)&Ks[row*264 + col] = *(const uint4*)(kb + (size_t)row * THD + col);
    }
    // stage V tile transposed: Vb[b][s][h][d] -> Vs[d][s_local]
#pragma unroll
    for (int it = 0; it < 4; ++it) {
      int c = t + it*256;
      int sl = c >> 5, col = (c & 31) * 8;
      uint4 v = *(const uint4*)(Vb + ((size_t)(b*TS + j*32 + sl) * TH + h) * THD + col);
      const unsigned short* pv = (const unsigned short*)&v;
#pragma unroll
      for (int e = 0; e < 8; ++e) Vs[(col + e)*40 + sl] = pv[e];
    }
    __syncthreads();

    // S = Q K^T
    f32x4 sacc[2];
    sacc[0] = 0.f; sacc[1] = 0.f;
#pragma unroll
    for (int nt = 0; nt < 2; ++nt)
#pragma unroll
      for (int kk = 0; kk < 8; ++kk) {
        bf16x8 kf = *(const bf16x8*)&Ks[(nt*16 + lr)*264 + kk*32 + lh*8];
        sacc[nt] = __builtin_amdgcn_mfma_f32_16x16x32_bf16(qf[kk], kf, sacc[nt], 0, 0, 0);
      }

    // online softmax (C layout: row = lh*4+r, col = nt*16+lr)
    float p[2][4], tmax[4], tsum[4], alpha[4];
    const int qrb = q0 + w*16 + lh*4;
#pragma unroll
    for (int r = 0; r < 4; ++r) tmax[r] = -__builtin_inff();
#pragma unroll
    for (int nt = 0; nt < 2; ++nt) {
      int kpos = j*32 + nt*16 + lr;
#pragma unroll
      for (int r = 0; r < 4; ++r) {
        float sv = sacc[nt][r] * 0.0625f;           // 1/sqrt(256)
        if (kpos > qrb + r) sv = -__builtin_inff(); // causal mask
        p[nt][r] = sv;
        tmax[r] = fmaxf(tmax[r], sv);
      }
    }
#pragma unroll
    for (int off = 1; off < 16; off <<= 1)
#pragma unroll
      for (int r = 0; r < 4; ++r) tmax[r] = fmaxf(tmax[r], __shfl_xor(tmax[r], off, 64));
#pragma unroll
    for (int r = 0; r < 4; ++r) {
      float mn = fmaxf(mrow[r], tmax[r]);
      alpha[r] = __expf(mrow[r] - mn);   // first tile: exp(-inf)=0
      mrow[r] = mn;
      tsum[r] = 0.f;
    }
#pragma unroll
    for (int nt = 0; nt < 2; ++nt)
#pragma unroll
      for (int r = 0; r < 4; ++r) {
        float pe = __expf(p[nt][r] - mrow[r]);      // masked -> exp(-inf)=0
        p[nt][r] = pe;
        tsum[r] += pe;
      }
#pragma unroll
    for (int off = 1; off < 16; off <<= 1)
#pragma unroll
      for (int r = 0; r < 4; ++r) tsum[r] += __shfl_xor(tsum[r], off, 64);
#pragma unroll
    for (int r = 0; r < 4; ++r) lrow[r] = lrow[r] * alpha[r] + tsum[r];
#pragma unroll
    for (int i = 0; i < 16; ++i)
#pragma unroll
      for (int r = 0; r < 4; ++r) oacc[i][r] *= alpha[r];

    // P: C layout -> A-fragment layout via padded LDS
#pragma unroll
    for (int nt = 0; nt < 2; ++nt)
#pragma unroll
      for (int r = 0; r < 4; ++r)
        Ps[w][(lh*4 + r)*40 + nt*16 + lr] = f2bf(p[nt][r]);
    __syncthreads();
    bf16x8 pf = *(const bf16x8*)&Ps[w][lr*40 + lh*8];

    // O += P V
#pragma unroll
    for (int dt = 0; dt < 16; ++dt) {
      bf16x8 vf = *(const bf16x8*)&Vs[(dt*16 + lr)*40 + lh*8];
      oacc[dt] = __builtin_amdgcn_mfma_f32_16x16x32_bf16(pf, vf, oacc[dt], 0, 0, 0);
    }
    __syncthreads();
  }

  // epilogue: O[b][s][h][d] bf16
#pragma unroll
  for (int dt = 0; dt < 16; ++dt)
#pragma unroll
    for (int r = 0; r < 4; ++r) {
      int s = q0 + w*16 + lh*4 + r;
      float val = oacc[dt][r] / lrow[r];
      O[((size_t)(b*TS + s) * TH + h) * THD + dt*16 + lr] = f2bf(val);
    }
}

// ---------------- launch ----------------
extern "C" void kernel_launch(void* const* d_in, const int* in_sizes, int n_in,
                              void* d_out, int out_size, void* d_ws, size_t ws_size,
                              hipStream_t stream) {
  const float* hs   = (const float*)d_in[0];
  const float* sinp = (const float*)d_in[1];
  const float* cosp = (const float*)d_in[2];
  const float* Wq   = (const float*)d_in[3];
  const float* Wk   = (const float*)d_in[4];
  const float* Wv   = (const float*)d_in[5];
  const float* Wo   = (const float*)d_in[6];

  const size_t NE = (size_t)TM * TD;   // 16,777,216 elements per [4096,4096] tensor
  const size_t BYTES = NE * 2;         // bf16 bytes
  char* ws = (char*)d_ws;
  unsigned short* hsb = (unsigned short*)(ws + 0*BYTES);
  unsigned short* Wqb = (unsigned short*)(ws + 1*BYTES);
  unsigned short* Wkb = (unsigned short*)(ws + 2*BYTES);
  unsigned short* Wvb = (unsigned short*)(ws + 3*BYTES);
  unsigned short* Wob = (unsigned short*)(ws + 4*BYTES);
  unsigned short* Qt  = (unsigned short*)(ws + 5*BYTES);  // [B,H,S,HD]
  unsigned short* Ktb = (unsigned short*)(ws + 6*BYTES);  // [B,H,S,HD]
  unsigned short* Vb  = (unsigned short*)(ws + 7*BYTES);  // [B,S,H,HD]
  unsigned short* Ob  = (unsigned short*)(ws + 8*BYTES);  // [B,S,H,HD] == [M,D]

  int n4 = (int)(NE / 4);
  int cvb = (n4 + 255) / 256;
  k_cvt<<<cvb, 256, 0, stream>>>(hs, hsb, n4);
  k_cvt<<<cvb, 256, 0, stream>>>(Wq, Wqb, n4);
  k_cvt<<<cvb, 256, 0, stream>>>(Wk, Wkb, n4);
  k_cvt<<<cvb, 256, 0, stream>>>(Wv, Wvb, n4);
  k_cvt<<<cvb, 256, 0, stream>>>(Wo, Wob, n4);

  dim3 gg(TD/128, TM/128);
  k_gemm<1><<<gg, 256, 0, stream>>>(hsb, Wqb, (void*)Qt,  sinp, cosp);
  k_gemm<1><<<gg, 256, 0, stream>>>(hsb, Wkb, (void*)Ktb, sinp, cosp);
  k_gemm<2><<<gg, 256, 0, stream>>>(hsb, Wvb, (void*)Vb,  nullptr, nullptr);

  k_fattn<<<dim3(TS/64, TB*TH), 256, 0, stream>>>(Qt, Ktb, Vb, Ob);

  k_gemm<0><<<gg, 256, 0, stream>>>(Ob, Wob, d_out, nullptr, nullptr);
}

// Round 2
// 1348.014 us; speedup vs baseline: 1.6209x; 1.6209x over previous
//
#include <hip/hip_runtime.h>
#include <cstdint>
#include <cstddef>

#define TB 2
#define TS 2048
#define TD 4096
#define TH 16
#define THD 256
#define TROT 64
#define TM (TB*TS)

typedef __attribute__((ext_vector_type(8))) short bf16x8;
typedef __attribute__((ext_vector_type(4))) float f32x4;

__device__ __forceinline__ unsigned short f2bf(float f) {
  union { float f; unsigned u; } v; v.f = f;
  return (unsigned short)((v.u + 0x7fffu + ((v.u >> 16) & 1u)) >> 16);
}

__device__ __forceinline__ void gld16(const void* g, void* l) {
  __builtin_amdgcn_global_load_lds(
      (const __attribute__((address_space(1))) unsigned int*)g,
      (__attribute__((address_space(3))) unsigned int*)l, 16, 0, 0);
}

// ---------------- fp32 -> bf16 convert (vectorized) ----------------
__global__ __launch_bounds__(256) void k_cvt(const float* __restrict__ x,
                                             unsigned short* __restrict__ y, int n4) {
  int i = blockIdx.x * 256 + threadIdx.x;
  if (i >= n4) return;
  float4 v = reinterpret_cast<const float4*>(x)[i];
  ushort4 o;
  o.x = f2bf(v.x); o.y = f2bf(v.y); o.z = f2bf(v.z); o.w = f2bf(v.w);
  reinterpret_cast<ushort4*>(y)[i] = o;
}

// ---------------- GEMM: C = A (MxK,bf16) @ W^T (W: NxK,bf16) ----------------
// m97 structure: 128x128 tile, BK=32, global_load_lds width=16, linear LDS.
// MODE 0: fp32 out, row-major [M,N]
// MODE 1: RoPE + transpose epilogue -> bf16 out [B,H,S,HD]
// MODE 2: V^T epilogue -> bf16 out [B,H,HD,S] (packed ushort4 along s)
template<int MODE>
__global__ __launch_bounds__(256) void k_gemm(
    const unsigned short* __restrict__ A, const unsigned short* __restrict__ W,
    void* __restrict__ out, const float* __restrict__ sinp, const float* __restrict__ cosp)
{
  __shared__ unsigned short As[128*32];
  __shared__ unsigned short Bs[128*32];
  const int K = TD;
  const int t = threadIdx.x;
  const int m0 = blockIdx.y * 128, n0 = blockIdx.x * 128;
  const int w = t >> 6, l = t & 63, lr = l & 15, lh = l >> 4;
  const int wr = (w >> 1) * 64, wc = (w & 1) * 64;

  // wave w stages rows [32w, 32w+32) of A and B: 2 x (64 lanes x 16B = 1KB = 16 rows)
  const int i0 = w * 2, i1 = w * 2 + 1;
  const size_t ao0 = (size_t)(m0 + i0*16 + (l >> 2)) * K + (l & 3) * 8;
  const size_t ao1 = (size_t)(m0 + i1*16 + (l >> 2)) * K + (l & 3) * 8;
  const size_t bo0 = (size_t)(n0 + i0*16 + (l >> 2)) * K + (l & 3) * 8;
  const size_t bo1 = (size_t)(n0 + i1*16 + (l >> 2)) * K + (l & 3) * 8;
  unsigned short* la0 = &As[i0 * 512];
  unsigned short* la1 = &As[i1 * 512];
  unsigned short* lb0 = &Bs[i0 * 512];
  unsigned short* lb1 = &Bs[i1 * 512];

  f32x4 acc[4][4];
#pragma unroll
  for (int i = 0; i < 4; ++i)
#pragma unroll
    for (int j = 0; j < 4; ++j) acc[i][j] = 0.f;

  for (int kt = 0; kt < K / 32; ++kt) {
    const int ko = kt * 32;
    __syncthreads();
    gld16(A + ao0 + ko, la0);
    gld16(A + ao1 + ko, la1);
    gld16(W + bo0 + ko, lb0);
    gld16(W + bo1 + ko, lb1);
    __syncthreads();
    bf16x8 af[4], bfr[4];
#pragma unroll
    for (int i = 0; i < 4; ++i) af[i]  = *(const bf16x8*)&As[(wr + i*16 + lr)*32 + lh*8];
#pragma unroll
    for (int i = 0; i < 4; ++i) bfr[i] = *(const bf16x8*)&Bs[(wc + i*16 + lr)*32 + lh*8];
#pragma unroll
    for (int i = 0; i < 4; ++i)
#pragma unroll
      for (int j = 0; j < 4; ++j)
        acc[i][j] = __builtin_amdgcn_mfma_f32_16x16x32_bf16(af[i], bfr[j], acc[i][j], 0, 0, 0);
  }

#pragma unroll
  for (int i = 0; i < 4; ++i)
#pragma unroll
    for (int j = 0; j < 4; ++j) {
      if constexpr (MODE == 2) {
        int row0 = m0 + wr + i*16 + lh*4;          // 4 consecutive s in acc[..][r]
        int col  = n0 + wc + j*16 + lr;
        int b = row0 >> 11, s = row0 & (TS - 1);
        int h = col >> 8, d = col & 255;
        ushort4 o;
        o.x = f2bf(acc[i][j][0]); o.y = f2bf(acc[i][j][1]);
        o.z = f2bf(acc[i][j][2]); o.w = f2bf(acc[i][j][3]);
        *(ushort4*)((unsigned short*)out + ((size_t)((b*TH + h)*THD + d)) * TS + s) = o;
      } else {
#pragma unroll
        for (int r = 0; r < 4; ++r) {
          int row = m0 + wr + i*16 + lh*4 + r;     // C layout: row=(l>>4)*4+r
          int col = n0 + wc + j*16 + lr;           //            col=l&15
          float x = acc[i][j][r];
          if constexpr (MODE == 0) {
            ((float*)out)[(size_t)row * TD + col] = x;
          } else {
            float part = __shfl_xor(x, 1, 64);     // partner d^1 lives in lane l^1
            int s = row & (TS - 1), b = row >> 11;
            int h = col >> 8, d = col & 255;
            float val = x;
            if (d < TROT) {
              float cc = cosp[s * TROT + d], ss = sinp[s * TROT + d];
              val = x * cc + ((d & 1) ? part : -part) * ss;  // GPT-J rotate_every_two
            }
            ((unsigned short*)out)[((size_t)(b * TH + h) * TS + s) * THD + d] = f2bf(val);
          }
        }
      }
    }
}

// ---------------- causal flash attention ----------------
// Qt,Kt: [B,H,S,HD] bf16.  Vt: [B,H,HD,S] bf16 (V^T).  O: [B,S,H,HD] bf16.
// block = 4 waves; wave w owns q rows [q0+16w, q0+16w+16); KV tile = 32.
// LPT: heaviest q-blocks dispatched first via qb = 31 - blockIdx.y.
__global__ __launch_bounds__(256) void k_fattn(
    const unsigned short* __restrict__ Qt, const unsigned short* __restrict__ Kt,
    const unsigned short* __restrict__ Vt, unsigned short* __restrict__ O)
{
  __shared__ unsigned short Ks[32*264];    // 32 x (256+8 pad)
  __shared__ unsigned short Vs[256*40];    // V^T tile: [d][s_local], 32+8 pad
  __shared__ unsigned short Ps[4*16*40];   // per-wave P relayout (wave-private)
  const int t = threadIdx.x, w = t >> 6, l = t & 63, lr = l & 15, lh = l >> 4;
  const int bh = blockIdx.x;
  const int qb = (gridDim.y - 1) - blockIdx.y;
  const int q0 = qb * 64;
  const int jmax = 2 * qb + 1;

  const unsigned short* kbase = Kt + (size_t)bh * TS * THD;
  const unsigned short* vbase = Vt + (size_t)bh * THD * TS;

  bf16x8 qf[8];
  const unsigned short* qb_ = Qt + ((size_t)bh * TS + q0 + w*16 + lr) * THD;
#pragma unroll
  for (int kk = 0; kk < 8; ++kk) qf[kk] = *(const bf16x8*)(qb_ + kk*32 + lh*8);

  f32x4 oacc[16];
#pragma unroll
  for (int i = 0; i < 16; ++i) oacc[i] = 0.f;
  float mrow[4] = {-__builtin_inff(), -__builtin_inff(), -__builtin_inff(), -__builtin_inff()};
  float lrow[4] = {0.f, 0.f, 0.f, 0.f};

  // staging maps (chunk c = t + it*256):
  //  K: row = c>>5 (32), col = (c&31)*8;  V: d = c>>2 (256), col = (c&3)*8
  uint4 ka[4], va[4];
#pragma unroll
  for (int it = 0; it < 4; ++it) {
    int c = t + it * 256;
    ka[it] = *(const uint4*)(kbase + (size_t)(c >> 5) * THD + (c & 31) * 8);
    va[it] = *(const uint4*)(vbase + (size_t)(c >> 2) * TS + (c & 3) * 8);
  }

  for (int j = 0; j <= jmax; ++j) {
    __syncthreads();
#pragma unroll
    for (int it = 0; it < 4; ++it) {
      int c = t + it * 256;
      *(uint4*)&Ks[(c >> 5) * 264 + (c & 31) * 8] = ka[it];
      *(uint4*)&Vs[(c >> 2) * 40  + (c & 3)  * 8] = va[it];
    }
    __syncthreads();

    if (j < jmax) {   // T14: issue next tile's loads, hide latency under compute
      int jn = (j + 1) * 32;
#pragma unroll
      for (int it = 0; it < 4; ++it) {
        int c = t + it * 256;
        ka[it] = *(const uint4*)(kbase + (size_t)(jn + (c >> 5)) * THD + (c & 31) * 8);
        va[it] = *(const uint4*)(vbase + (size_t)(c >> 2) * TS + jn + (c & 3) * 8);
      }
    }

    // S = Q K^T
    f32x4 sacc[2];
    sacc[0] = 0.f; sacc[1] = 0.f;
#pragma unroll
    for (int nt = 0; nt < 2; ++nt)
#pragma unroll
      for (int kk = 0; kk < 8; ++kk) {
        bf16x8 kf = *(const bf16x8*)&Ks[(nt*16 + lr)*264 + kk*32 + lh*8];
        sacc[nt] = __builtin_amdgcn_mfma_f32_16x16x32_bf16(qf[kk], kf, sacc[nt], 0, 0, 0);
      }

    // online softmax (C layout: row = lh*4+r, col = nt*16+lr)
    float p[2][4], tmax[4], tsum[4], alpha[4];
    const int qrb = q0 + w*16 + lh*4;
#pragma unroll
    for (int r = 0; r < 4; ++r) tmax[r] = -__builtin_inff();
#pragma unroll
    for (int nt = 0; nt < 2; ++nt) {
      int kpos = j*32 + nt*16 + lr;
#pragma unroll
      for (int r = 0; r < 4; ++r) {
        float sv = sacc[nt][r] * 0.0625f;           // 1/sqrt(256)
        if (kpos > qrb + r) sv = -__builtin_inff(); // causal mask
        p[nt][r] = sv;
        tmax[r] = fmaxf(tmax[r], sv);
      }
    }
#pragma unroll
    for (int off = 1; off < 16; off <<= 1)
#pragma unroll
      for (int r = 0; r < 4; ++r) tmax[r] = fmaxf(tmax[r], __shfl_xor(tmax[r], off, 64));
#pragma unroll
    for (int r = 0; r < 4; ++r) {
      float mn = fmaxf(mrow[r], tmax[r]);
      alpha[r] = __expf(mrow[r] - mn);
      mrow[r] = mn;
      tsum[r] = 0.f;
    }
#pragma unroll
    for (int nt = 0; nt < 2; ++nt)
#pragma unroll
      for (int r = 0; r < 4; ++r) {
        float pe = __expf(p[nt][r] - mrow[r]);
        p[nt][r] = pe;
        tsum[r] += pe;
      }
#pragma unroll
    for (int off = 1; off < 16; off <<= 1)
#pragma unroll
      for (int r = 0; r < 4; ++r) tsum[r] += __shfl_xor(tsum[r], off, 64);
#pragma unroll
    for (int r = 0; r < 4; ++r) lrow[r] = lrow[r] * alpha[r] + tsum[r];
#pragma unroll
    for (int i = 0; i < 16; ++i)
#pragma unroll
      for (int r = 0; r < 4; ++r) oacc[i][r] *= alpha[r];

    // P: C layout -> A-fragment layout via wave-private LDS (no barrier needed)
#pragma unroll
    for (int nt = 0; nt < 2; ++nt)
#pragma unroll
      for (int r = 0; r < 4; ++r)
        Ps[w*640 + (lh*4 + r)*40 + nt*16 + lr] = f2bf(p[nt][r]);
    bf16x8 pf = *(const bf16x8*)&Ps[w*640 + lr*40 + lh*8];

    // O += P V
#pragma unroll
    for (int dt = 0; dt < 16; ++dt) {
      bf16x8 vf = *(const bf16x8*)&Vs[(dt*16 + lr)*40 + lh*8];
      oacc[dt] = __builtin_amdgcn_mfma_f32_16x16x32_bf16(pf, vf, oacc[dt], 0, 0, 0);
    }
  }

  // epilogue: O[b][s][h][d] bf16
  const int b = bh >> 4, h = bh & 15;
  float inv[4];
#pragma unroll
  for (int r = 0; r < 4; ++r) inv[r] = 1.f / lrow[r];
#pragma unroll
  for (int dt = 0; dt < 16; ++dt)
#pragma unroll
    for (int r = 0; r < 4; ++r) {
      int s = q0 + w*16 + lh*4 + r;
      O[((size_t)(b*TS + s) * TH + h) * THD + dt*16 + lr] = f2bf(oacc[dt][r] * inv[r]);
    }
}

// ---------------- launch ----------------
extern "C" void kernel_launch(void* const* d_in, const int* in_sizes, int n_in,
                              void* d_out, int out_size, void* d_ws, size_t ws_size,
                              hipStream_t stream) {
  const float* hs   = (const float*)d_in[0];
  const float* sinp = (const float*)d_in[1];
  const float* cosp = (const float*)d_in[2];
  const float* Wq   = (const float*)d_in[3];
  const float* Wk   = (const float*)d_in[4];
  const float* Wv   = (const float*)d_in[5];
  const float* Wo   = (const float*)d_in[6];

  const size_t NE = (size_t)TM * TD;
  const size_t BYTES = NE * 2;
  char* ws = (char*)d_ws;
  unsigned short* hsb = (unsigned short*)(ws + 0*BYTES);
  unsigned short* Wqb = (unsigned short*)(ws + 1*BYTES);
  unsigned short* Wkb = (unsigned short*)(ws + 2*BYTES);
  unsigned short* Wvb = (unsigned short*)(ws + 3*BYTES);
  unsigned short* Wob = (unsigned short*)(ws + 4*BYTES);
  unsigned short* Qt  = (unsigned short*)(ws + 5*BYTES);  // [B,H,S,HD]
  unsigned short* Ktb = (unsigned short*)(ws + 6*BYTES);  // [B,H,S,HD]
  unsigned short* Vtb = (unsigned short*)(ws + 7*BYTES);  // [B,H,HD,S]  (V^T)
  unsigned short* Ob  = (unsigned short*)(ws + 8*BYTES);  // [B,S,H,HD] == [M,D]

  int n4 = (int)(NE / 4);
  int cvb = (n4 + 255) / 256;
  k_cvt<<<cvb, 256, 0, stream>>>(hs, hsb, n4);
  k_cvt<<<cvb, 256, 0, stream>>>(Wq, Wqb, n4);
  k_cvt<<<cvb, 256, 0, stream>>>(Wk, Wkb, n4);
  k_cvt<<<cvb, 256, 0, stream>>>(Wv, Wvb, n4);
  k_cvt<<<cvb, 256, 0, stream>>>(Wo, Wob, n4);

  dim3 gg(TD/128, TM/128);
  k_gemm<1><<<gg, 256, 0, stream>>>(hsb, Wqb, (void*)Qt,  sinp, cosp);
  k_gemm<1><<<gg, 256, 0, stream>>>(hsb, Wkb, (void*)Ktb, sinp, cosp);
  k_gemm<2><<<gg, 256, 0, stream>>>(hsb, Wvb, (void*)Vtb, nullptr, nullptr);

  k_fattn<<<dim3(TB*TH, TS/64), 256, 0, stream>>>(Qt, Ktb, Vtb, Ob);

  k_gemm<0><<<gg, 256, 0, stream>>>(Ob, Wob, d_out, nullptr, nullptr);
}